// Round 12
// baseline (371.851 us; speedup 1.0000x reference)
//
#include <hip/hip_runtime.h>

// GAT 3-layer forward, MI355X gfx950.
// R12: gemm_l2 retiled BM=320 x BN=256 (grid 256 = 1/CU, zero tail): halves
// logical A traffic through L3 (16 -> 8 re-reads); XCD x owns N-column x so
// each XCD's 1MB B panel is L2-resident. Asymmetric staging w/ per-role vmcnt.
// Rest frozen from R11 (head-major hbuf, wave-per-(v,h) agg, L1 linearity).

typedef __attribute__((ext_vector_type(8))) short bf16x8;
typedef __attribute__((ext_vector_type(4))) float f32x4;

#define DEVINL __device__ __forceinline__

static constexpr int NN   = 10000;
static constexpr int NE   = 160000;
static constexpr int MPAD = 10240;   // 32*320, 80*128
static constexpr int DIN  = 64;
static constexpr int CCH  = 256;
static constexpr int NH   = 8;
static constexpr int F12  = 2048;    // NH * CCH

DEVINL unsigned short f2bf(float x){
  unsigned u = __float_as_uint(x);
  u += 0x7fffu + ((u >> 16) & 1u);           // RNE
  return (unsigned short)(u >> 16);
}
DEVINL float bf2f(unsigned short h){ return __uint_as_float(((unsigned)h) << 16); }

DEVINL void gload_lds16(const unsigned short* g, unsigned short* lds){
  __builtin_amdgcn_global_load_lds(
      (__attribute__((address_space(1))) unsigned int*)(g),
      (__attribute__((address_space(3))) unsigned int*)(lds), 16, 0, 0);
}

// ---- W [K][Nn] f32 -> Wt [Nn][K] bf16
__global__ __launch_bounds__(256) void transpose_cvt_kernel(const float* __restrict__ W,
                                                            unsigned short* __restrict__ Wt,
                                                            int K, int Nn){
  __shared__ float tile[32][33];
  int k0 = blockIdx.x*32, n0 = blockIdx.y*32;
  int tx = threadIdx.x & 31, ty = threadIdx.x >> 5;
  #pragma unroll
  for (int r = ty; r < 32; r += 8) tile[r][tx] = W[(size_t)(k0+r)*Nn + n0 + tx];
  __syncthreads();
  #pragma unroll
  for (int r = ty; r < 32; r += 8) Wt[(size_t)(n0+r)*K + k0 + tx] = f2bf(tile[tx][r]);
}

// ---- CSR build
__global__ __launch_bounds__(256) void hist_kernel(const int* __restrict__ dst,
                                                   int* __restrict__ deg, int E_){
  int i = blockIdx.x*256 + threadIdx.x;
  if (i < E_) atomicAdd(&deg[dst[i]], 1);
}

__global__ __launch_bounds__(256) void scan_kernel(const int* __restrict__ deg,
                                                   int* __restrict__ off, int n){
  const int CH = (n + 255) / 256;
  int t = threadIdx.x;
  int lo = t*CH, hi = min(lo + CH, n);
  int s = 0;
  for (int i = lo; i < hi; i++) s += deg[i];
  __shared__ int ws[256];
  ws[t] = s;
  __syncthreads();
  for (int d = 1; d < 256; d <<= 1){
    int v = (t >= d) ? ws[t-d] : 0;
    __syncthreads();
    ws[t] += v;
    __syncthreads();
  }
  int run = ws[t] - s;
  for (int i = lo; i < hi; i++){ off[i] = run; run += deg[i]; }
  if (t == 255) off[n] = ws[255];
}

__global__ __launch_bounds__(256) void scatter_kernel(const int* __restrict__ src,
                                                      const int* __restrict__ dst,
                                                      const int* __restrict__ off,
                                                      int* __restrict__ cursor,
                                                      int* __restrict__ csrc, int E_){
  int i = blockIdx.x*256 + threadIdx.x;
  if (i >= E_) return;
  int d = dst[i];
  int pI = atomicAdd(&cursor[d], 1);
  csrc[off[d] + pI] = src[i];
}

// ---- Wa1[c][i] = sum_j W1[c][h*256+j] * a1{s,d}[h][j]
__global__ __launch_bounds__(256) void wa1_kernel(const float* __restrict__ W1,
                                                  const float* __restrict__ a1s,
                                                  const float* __restrict__ a1d,
                                                  float* __restrict__ Wa1){
  int t = blockIdx.x*256 + threadIdx.x;
  if (t >= 64*16) return;
  int c = t >> 4, i = t & 15;
  int h = i & 7;
  const float* a = (i < 8) ? a1s : a1d;
  float s = 0.f;
  #pragma unroll 8
  for (int j = 0; j < 256; j++) s = fmaf(W1[(size_t)c*F12 + h*256 + j], a[h*256 + j], s);
  Wa1[c*16 + i] = s;
}

// ---- layer-1 logits straight from x
__global__ __launch_bounds__(256) void logits1_kernel(const float* __restrict__ x,
                                                      const float* __restrict__ Wa1,
                                                      float* __restrict__ als,
                                                      float* __restrict__ ald){
  __shared__ float wa[64*16];
  for (int i = threadIdx.x; i < 64*16; i += 256) wa[i] = Wa1[i];
  __syncthreads();
  int gid = blockIdx.x*256 + threadIdx.x;
  int v = gid >> 4, i = gid & 15;
  if (v >= NN) return;
  float s = 0.f;
  #pragma unroll
  for (int c = 0; c < 64; c++) s = fmaf(x[(size_t)v*64 + c], wa[c*16 + i], s);
  if (i < 8) als[v*8 + i] = s;
  else       ald[v*8 + (i - 8)] = s;
}

// ---- layer-1 aggregation in INPUT space
__global__ __launch_bounds__(256) void agg1_kernel(const float* __restrict__ x,
                                                   const int* __restrict__ off,
                                                   const int* __restrict__ csrc,
                                                   const float* __restrict__ als,
                                                   const float* __restrict__ ald,
                                                   unsigned short* __restrict__ Xa){
  const int wv = threadIdx.x >> 6, lane = threadIdx.x & 63;
  const int v = blockIdx.x*4 + wv;
  if (v >= NN) return;
  const int e0 = off[v], deg = off[v+1] - e0;

  float aldv[8];
  #pragma unroll
  for (int h = 0; h < 8; h++) aldv[h] = ald[v*8 + h];

  float m[8], s[8];
  #pragma unroll
  for (int h = 0; h < 8; h++){ m[h] = -1e30f; s[h] = 0.f; }
  for (int base = 0; base < deg; base += 64){
    int i = base + lane;
    bool act = i < deg;
    int u = act ? csrc[e0 + i] : 0;
    float e[8];
    #pragma unroll
    for (int h = 0; h < 8; h++){
      float xe = act ? (als[u*8 + h] + aldv[h]) : -1e30f;
      e[h] = xe > 0.f ? xe : 0.2f*xe;
    }
    #pragma unroll
    for (int h = 0; h < 8; h++){
      float t = e[h];
      #pragma unroll
      for (int d = 1; d < 64; d <<= 1) t = fmaxf(t, __shfl_xor(t, d));
      float nm = fmaxf(m[h], t);
      float cs = act ? __expf(e[h] - nm) : 0.f;
      #pragma unroll
      for (int d = 1; d < 64; d <<= 1) cs += __shfl_xor(cs, d);
      s[h] = s[h]*__expf(m[h] - nm) + cs;
      m[h] = nm;
    }
  }
  float sinv[8];
  #pragma unroll
  for (int h = 0; h < 8; h++) sinv[h] = 1.f / (s[h] + 1e-16f);

  float acc[8];
  #pragma unroll
  for (int h = 0; h < 8; h++) acc[h] = 0.f;
  for (int j = 0; j < deg; j++){
    int u = csrc[e0 + j];
    float xv = x[(size_t)u*64 + lane];
    #pragma unroll
    for (int h = 0; h < 8; h++){
      float xe = als[u*8 + h] + aldv[h];
      xe = xe > 0.f ? xe : 0.2f*xe;
      float a = __expf(xe - m[h]) * sinv[h];
      acc[h] = fmaf(a, xv, acc[h]);
    }
  }
  #pragma unroll
  for (int h = 0; h < 8; h++)
    Xa[(size_t)v*512 + h*64 + lane] = f2bf(acc[h]);
}

// ---- layer-1 GEMM per head with fused bias+ELU
__global__ __launch_bounds__(256) void gemm_l1_kernel(
    const unsigned short* __restrict__ Xa,    // [MPAD][8][64]
    const unsigned short* __restrict__ Wt1,   // [2048][64]
    const float* __restrict__ b1,
    unsigned short* __restrict__ actA)        // [MPAD][2048]
{
  __shared__ __align__(16) unsigned short As[2][128*32];
  __shared__ __align__(16) unsigned short Bs[2][256*32];
  const int wave = threadIdx.x >> 6, lane = threadIdx.x & 63;
  const int wm = wave >> 1, wn = wave & 1;
  const size_t m0 = (size_t)blockIdx.x * 128;
  const int h = blockIdx.y;
  const int lr = lane >> 2, l3 = lane & 3;

  #pragma unroll
  for (int sB = 0; sB < 2; sB++){
    #pragma unroll
    for (int j = 0; j < 2; j++){
      int rb = (wave*2 + j)*16;
      int row = rb + lr;
      int kc = l3 ^ ((row >> 1) & 3);
      gload_lds16(Xa + (m0 + row)*512 + h*64 + sB*32 + kc*8, &As[sB][rb*32]);
    }
    #pragma unroll
    for (int j = 0; j < 4; j++){
      int rb = (wave*4 + j)*16;
      int row = rb + lr;
      int kc = l3 ^ ((row >> 1) & 3);
      gload_lds16(Wt1 + (size_t)(h*256 + row)*64 + sB*32 + kc*8, &Bs[sB][rb*32]);
    }
  }
  asm volatile("s_waitcnt vmcnt(0)" ::: "memory");
  __syncthreads();

  f32x4 acc[4][8];
  #pragma unroll
  for (int i = 0; i < 4; i++)
    #pragma unroll
    for (int j = 0; j < 8; j++) acc[i][j] = (f32x4){0.f,0.f,0.f,0.f};

  const int rl = lane & 15, q = lane >> 4;
  #pragma unroll
  for (int sB = 0; sB < 2; sB++){
    bf16x8 af[4], bfr[8];
    #pragma unroll
    for (int mm = 0; mm < 4; mm++){
      int row = wm*64 + mm*16 + rl;
      int ch = q ^ ((row >> 1) & 3);
      af[mm] = *(const bf16x8*)&As[sB][row*32 + ch*8];
    }
    #pragma unroll
    for (int n = 0; n < 8; n++){
      int row = wn*128 + n*16 + rl;
      int ch = q ^ ((row >> 1) & 3);
      bfr[n] = *(const bf16x8*)&Bs[sB][row*32 + ch*8];
    }
    #pragma unroll
    for (int mm = 0; mm < 4; mm++)
      #pragma unroll
      for (int n = 0; n < 8; n++)
        acc[mm][n] = __builtin_amdgcn_mfma_f32_16x16x32_bf16(af[mm], bfr[n], acc[mm][n], 0, 0, 0);
  }

  #pragma unroll
  for (int mm = 0; mm < 4; mm++)
    #pragma unroll
    for (int n = 0; n < 8; n++)
      #pragma unroll
      for (int r = 0; r < 4; r++){
        size_t row = m0 + wm*64 + mm*16 + q*4 + r;
        int col = wn*128 + n*16 + rl;
        float o = acc[mm][n][r] + b1[h*256 + col];
        o = o > 0.f ? o : (__expf(o) - 1.f);
        actA[row*F12 + h*256 + col] = f2bf(o);
      }
}

// ---- layer-2 GEMM: BM=320, BN=256, BK=32 -> grid 32x8 = 256 = 1/CU.
// XCD x owns N-column x (B panel 1MB L2-resident per XCD; A streams via L3,
// logical A traffic halved vs BN=128). 512 thr / 8 waves (2Mx4N), per-wave
// 160x64. Ring-3 LDS 108KB. Asymmetric staging: waves 0-3 3A+2B (vmcnt 5),
// waves 4-7 2A+2B (vmcnt 4), lead-2. Head-major epilogue (BN=256 = 1 head).
__global__ __launch_bounds__(512, 1) void gemm_l2_kernel(
    const unsigned short* __restrict__ A,
    const unsigned short* __restrict__ Bt,
    unsigned short* __restrict__ Chm,         // [8][MPAD][256]
    int K)
{
  __shared__ __align__(16) unsigned short As[3][320*32];   // 3 x 20KB
  __shared__ __align__(16) unsigned short Bs[3][256*32];   // 3 x 16KB

  const int tid  = threadIdx.x;
  const int wave = tid >> 6, lane = tid & 63;
  const int wm = wave >> 2, wn = wave & 3;          // 2Mx4N, per-wave 160x64

  const int xcd = blockIdx.x & 7;                   // N column (head)
  const int loc = blockIdx.x >> 3;                  // M tile 0..31
  const size_t m0 = (size_t)loc * 320;
  const size_t n0 = (size_t)xcd * 256;

  f32x4 acc[10][4];
  #pragma unroll
  for (int i = 0; i < 10; i++)
    #pragma unroll
    for (int j = 0; j < 4; j++) acc[i][j] = (f32x4){0.f,0.f,0.f,0.f};

  const int lr = lane >> 2;        // row within 16-row issue
  const int l3 = lane & 3;         // 16B chunk slot

  // A: 20 issues. waves 0-3 -> issues w*3+{0,1,2}; waves 4-7 -> 12+(w-4)*2+{0,1}
  const int nA    = (wave < 4) ? 3 : 2;
  const int aBase = (wave < 4) ? wave*3 : 12 + (wave - 4)*2;
  auto stageA = [&](int slot, int k0, int i){
    const int rb  = (aBase + i) * 16;
    const int row = rb + lr;
    const int kc  = l3 ^ ((row >> 1) & 3);
    gload_lds16(A + (m0 + row)*(size_t)K + k0 + kc*8, &As[slot][rb*32]);
  };
  // B: 16 issues, 2 per wave
  auto stageB = [&](int slot, int k0, int i){
    const int rb  = (wave*2 + i) * 16;
    const int row = rb + lr;
    const int kc  = l3 ^ ((row >> 1) & 3);
    gload_lds16(Bt + (n0 + row)*(size_t)K + k0 + kc*8, &Bs[slot][rb*32]);
  };
  auto stageTile = [&](int T){
    const int slot = T % 3, k0 = T << 5;
    for (int i = 0; i < nA; i++) stageA(slot, k0, i);
    stageB(slot, k0, 0); stageB(slot, k0, 1);
  };

  const int nt = K >> 5;            // 64
  stageTile(0);
  stageTile(1);

  const int rl = lane & 15;
  const int q  = lane >> 4;

  for (int T = 0; T < nt; ++T){
    if (T + 1 < nt){
      if (wave < 4) asm volatile("s_waitcnt vmcnt(5)" ::: "memory");
      else          asm volatile("s_waitcnt vmcnt(4)" ::: "memory");
    } else {
      asm volatile("s_waitcnt vmcnt(0)" ::: "memory");
    }
    __builtin_amdgcn_s_barrier();

    const int slot = T % 3;
    const bool st  = (T + 2 < nt);
    const int s2   = (T + 2) % 3;
    const int k2   = (T + 2) << 5;

    bf16x8 bfr[4], af[5];
    #pragma unroll
    for (int n = 0; n < 4; n++){
      const int row = wn*64 + n*16 + rl;
      const int ch  = q ^ ((row >> 1) & 3);
      bfr[n] = *(const bf16x8*)&Bs[slot][row*32 + ch*8];
    }
    // phase 0: A frags 0-4; stage this wave's A issues; MFMA 20
    #pragma unroll
    for (int m = 0; m < 5; m++){
      const int row = wm*160 + m*16 + rl;
      const int ch  = q ^ ((row >> 1) & 3);
      af[m] = *(const bf16x8*)&As[slot][row*32 + ch*8];
    }
    if (st){ for (int i = 0; i < nA; i++) stageA(s2, k2, i); }
    asm volatile("s_waitcnt lgkmcnt(0)" ::: "memory");
    __builtin_amdgcn_sched_barrier(0);
    __builtin_amdgcn_s_setprio(1);
    #pragma unroll
    for (int m = 0; m < 5; m++)
      #pragma unroll
      for (int n = 0; n < 4; n++)
        acc[m][n] = __builtin_amdgcn_mfma_f32_16x16x32_bf16(af[m], bfr[n], acc[m][n], 0, 0, 0);
    __builtin_amdgcn_s_setprio(0);
    __builtin_amdgcn_sched_barrier(0);
    // phase 1: A frags 5-9; stage B issues; MFMA 20
    #pragma unroll
    for (int m = 0; m < 5; m++){
      const int row = wm*160 + (m+5)*16 + rl;
      const int ch  = q ^ ((row >> 1) & 3);
      af[m] = *(const bf16x8*)&As[slot][row*32 + ch*8];
    }
    if (st){ stageB(s2, k2, 0); stageB(s2, k2, 1); }
    asm volatile("s_waitcnt lgkmcnt(0)" ::: "memory");
    __builtin_amdgcn_sched_barrier(0);
    __builtin_amdgcn_s_setprio(1);
    #pragma unroll
    for (int m = 0; m < 5; m++)
      #pragma unroll
      for (int n = 0; n < 4; n++)
        acc[m+5][n] = __builtin_amdgcn_mfma_f32_16x16x32_bf16(af[m], bfr[n], acc[m+5][n], 0, 0, 0);
    __builtin_amdgcn_s_setprio(0);
  }

  const int head = xcd;
  #pragma unroll
  for (int m = 0; m < 10; m++)
    #pragma unroll
    for (int n = 0; n < 4; n++)
      #pragma unroll
      for (int r = 0; r < 4; r++){
        size_t row = m0 + wm*160 + m*16 + q*4 + r;
        int ch = wn*64 + n*16 + rl;
        Chm[((size_t)head*MPAD + row)*CCH + ch] = f2bf(acc[m][n][r]);
      }
}

// ---- generic 128x128 GEMM (layer 3; row-major C)
__global__ __launch_bounds__(256, 2) void gemm_bt_kernel(
    const unsigned short* __restrict__ A,
    const unsigned short* __restrict__ Bt,
    unsigned short* __restrict__ C,
    int K, int Nn)
{
  __shared__ __align__(16) unsigned short As[2][128*32];
  __shared__ __align__(16) unsigned short Bs[2][128*32];
  const int tid  = threadIdx.x;
  const int wave = tid >> 6, lane = tid & 63;
  const int wr = wave >> 1, wc = wave & 1;
  const size_t m0 = (size_t)blockIdx.x * 128;
  const size_t n0 = (size_t)blockIdx.y * 128;

  const int l4 = lane >> 2;
  const int lc = lane & 3;

  f32x4 acc[4][4];
  #pragma unroll
  for (int i = 0; i < 4; i++)
    #pragma unroll
    for (int j = 0; j < 4; j++) acc[i][j] = (f32x4){0.f,0.f,0.f,0.f};

  auto stage = [&](int buf, int kt){
    const int k0 = kt << 5;
    #pragma unroll
    for (int half = 0; half < 2; ++half){
      const int rb  = (wave + half*4) * 16;
      const int row = rb + l4;
      const int kc  = lc ^ ((row >> 1) & 3);
      gload_lds16(A + ((m0 + row)*(size_t)K + k0 + kc*8), &As[buf][rb*32]);
    }
    #pragma unroll
    for (int half = 0; half < 2; ++half){
      const int rb  = (wave + half*4) * 16;
      const int row = rb + l4;
      const int kc  = lc ^ ((row >> 1) & 3);
      gload_lds16(Bt + ((n0 + row)*(size_t)K + k0 + kc*8), &Bs[buf][rb*32]);
    }
  };

  const int nt = K >> 5;
  stage(0, 0);
  __syncthreads();

  const int rl = lane & 15;
  const int q  = lane >> 4;

  int cur = 0;
  for (int t = 0; t < nt; ++t){
    if (t + 1 < nt) stage(cur ^ 1, t + 1);
    bf16x8 af[4], bfr[4];
    #pragma unroll
    for (int m = 0; m < 4; m++){
      int row = wr*64 + m*16 + rl;
      int ch  = q ^ ((row >> 1) & 3);
      af[m] = *(const bf16x8*)&As[cur][row*32 + ch*8];
    }
    #pragma unroll
    for (int n = 0; n < 4; n++){
      int row = wc*64 + n*16 + rl;
      int ch  = q ^ ((row >> 1) & 3);
      bfr[n] = *(const bf16x8*)&Bs[cur][row*32 + ch*8];
    }
    #pragma unroll
    for (int m = 0; m < 4; m++)
      #pragma unroll
      for (int n = 0; n < 4; n++)
        acc[m][n] = __builtin_amdgcn_mfma_f32_16x16x32_bf16(af[m], bfr[n], acc[m][n], 0, 0, 0);
    __syncthreads();
    cur ^= 1;
  }

  #pragma unroll
  for (int m = 0; m < 4; m++)
    #pragma unroll
    for (int n = 0; n < 4; n++)
      #pragma unroll
      for (int r = 0; r < 4; r++){
        size_t row = m0 + wr*64 + m*16 + q*4 + r;
        size_t col = n0 + wc*64 + n*16 + rl;
        C[row*(size_t)Nn + col] = f2bf(acc[m][n][r]);
      }
}

// ---- attention logits, head-major Hm [heads][MPAD][256]
__global__ __launch_bounds__(256) void logits_kernel(const unsigned short* __restrict__ Hm,
                                                     const float* __restrict__ aws,
                                                     const float* __restrict__ awd,
                                                     float* __restrict__ als,
                                                     float* __restrict__ ald,
                                                     int heads){
  int gw   = (blockIdx.x*256 + threadIdx.x) >> 6;
  int lane = threadIdx.x & 63;
  int node = gw / heads;
  int head = gw - node*heads;
  if (node >= NN) return;
  const unsigned short* hp = Hm + ((size_t)head*MPAD + node)*CCH + lane*4;
  const float* wsp = aws + head*CCH + lane*4;
  const float* wdp = awd + head*CCH + lane*4;
  float s = 0.f, d = 0.f;
  #pragma unroll
  for (int j = 0; j < 4; j++){
    float hv = bf2f(hp[j]);
    s = fmaf(hv, wsp[j], s);
    d = fmaf(hv, wdp[j], d);
  }
  #pragma unroll
  for (int m = 1; m < 64; m <<= 1){ s += __shfl_xor(s, m); d += __shfl_xor(d, m); }
  if (lane == 0){ als[node*heads + head] = s; ald[node*heads + head] = d; }
}

// ---- wave-per-(v,head) segment softmax + aggregation + bias + ELU
template<int NHD>
__global__ __launch_bounds__(256) void aggw_kernel(
    const unsigned short* __restrict__ Hm,
    const int* __restrict__ off, const int* __restrict__ csrc,
    const float* __restrict__ als, const float* __restrict__ ald,
    const float* __restrict__ bias,
    unsigned short* __restrict__ actout,
    float* __restrict__ fout)
{
  const int wv = threadIdx.x >> 6, lane = threadIdx.x & 63;
  int v, h;
  if constexpr (NHD == 8){
    h = blockIdx.x & 7;
    v = (blockIdx.x >> 3) * 4 + wv;
  } else {
    h = 0;
    v = blockIdx.x * 4 + wv;
  }
  if (v >= NN) return;
  const int e0 = off[v], deg = off[v+1] - e0;
  const float aldv = ald[v*NHD + h];

  __shared__ float al_sh[4][64];
  __shared__ int   u_sh[4][64];

  float mloc = -1e30f;
  for (int i = lane; i < deg; i += 64){
    int u = csrc[e0 + i];
    float xe = als[u*NHD + h] + aldv;
    xe = xe > 0.f ? xe : 0.2f*xe;
    mloc = fmaxf(mloc, xe);
  }
  #pragma unroll
  for (int d = 1; d < 64; d <<= 1) mloc = fmaxf(mloc, __shfl_xor(mloc, d));
  float sloc = 0.f;
  for (int i = lane; i < deg; i += 64){
    int u = csrc[e0 + i];
    float xe = als[u*NHD + h] + aldv;
    xe = xe > 0.f ? xe : 0.2f*xe;
    sloc += __expf(xe - mloc);
  }
  #pragma unroll
  for (int d = 1; d < 64; d <<= 1) sloc += __shfl_xor(sloc, d);
  const float sinv = 1.f / (sloc + 1e-16f);

  const unsigned short* hB = Hm + (size_t)h*MPAD*CCH + lane*4;
  float a0c = 0.f, a1c = 0.f, a2c = 0.f, a3c = 0.f;

  for (int base = 0; base < deg; base += 64){
    const int nch = min(deg - base, 64);
    if (lane < nch){
      int u = csrc[e0 + base + lane];
      u_sh[wv][lane] = u;
      float xe = als[u*NHD + h] + aldv;
      xe = xe > 0.f ? xe : 0.2f*xe;
      al_sh[wv][lane] = __expf(xe - mloc) * sinv;
    }
    int j = 0;
    for (; j + 4 <= nch; j += 4){
      const int u0 = u_sh[wv][j],   u1 = u_sh[wv][j+1];
      const int u2 = u_sh[wv][j+2], u3 = u_sh[wv][j+3];
      const float b0 = al_sh[wv][j],   b1v = al_sh[wv][j+1];
      const float b2 = al_sh[wv][j+2], b3v = al_sh[wv][j+3];
      uint2 w0 = *(const uint2*)(hB + (size_t)u0*CCH);
      uint2 w1 = *(const uint2*)(hB + (size_t)u1*CCH);
      uint2 w2 = *(const uint2*)(hB + (size_t)u2*CCH);
      uint2 w3 = *(const uint2*)(hB + (size_t)u3*CCH);
      a0c = fmaf(b0, bf2f((unsigned short)(w0.x & 0xffff)), a0c);
      a1c = fmaf(b0, bf2f((unsigned short)(w0.x >> 16)),    a1c);
      a2c = fmaf(b0, bf2f((unsigned short)(w0.y & 0xffff)), a2c);
      a3c = fmaf(b0, bf2f((unsigned short)(w0.y >> 16)),    a3c);
      a0c = fmaf(b1v, bf2f((unsigned short)(w1.x & 0xffff)), a0c);
      a1c = fmaf(b1v, bf2f((unsigned short)(w1.x >> 16)),    a1c);
      a2c = fmaf(b1v, bf2f((unsigned short)(w1.y & 0xffff)), a2c);
      a3c = fmaf(b1v, bf2f((unsigned short)(w1.y >> 16)),    a3c);
      a0c = fmaf(b2, bf2f((unsigned short)(w2.x & 0xffff)), a0c);
      a1c = fmaf(b2, bf2f((unsigned short)(w2.x >> 16)),    a1c);
      a2c = fmaf(b2, bf2f((unsigned short)(w2.y & 0xffff)), a2c);
      a3c = fmaf(b2, bf2f((unsigned short)(w2.y >> 16)),    a3c);
      a0c = fmaf(b3v, bf2f((unsigned short)(w3.x & 0xffff)), a0c);
      a1c = fmaf(b3v, bf2f((unsigned short)(w3.x >> 16)),    a1c);
      a2c = fmaf(b3v, bf2f((unsigned short)(w3.y & 0xffff)), a2c);
      a3c = fmaf(b3v, bf2f((unsigned short)(w3.y >> 16)),    a3c);
    }
    for (; j < nch; j++){
      const int u = u_sh[wv][j];
      const float a = al_sh[wv][j];
      uint2 w = *(const uint2*)(hB + (size_t)u*CCH);
      a0c = fmaf(a, bf2f((unsigned short)(w.x & 0xffff)), a0c);
      a1c = fmaf(a, bf2f((unsigned short)(w.x >> 16)),    a1c);
      a2c = fmaf(a, bf2f((unsigned short)(w.y & 0xffff)), a2c);
      a3c = fmaf(a, bf2f((unsigned short)(w.y >> 16)),    a3c);
    }
  }

  const int c0 = h*CCH + lane*4;
  float o0 = a0c + bias[c0],     o1 = a1c + bias[c0 + 1];
  float o2 = a2c + bias[c0 + 2], o3 = a3c + bias[c0 + 3];
  o0 = o0 > 0.f ? o0 : (__expf(o0) - 1.f);
  o1 = o1 > 0.f ? o1 : (__expf(o1) - 1.f);
  o2 = o2 > 0.f ? o2 : (__expf(o2) - 1.f);
  o3 = o3 > 0.f ? o3 : (__expf(o3) - 1.f);
  if constexpr (NHD == 8){
    uint2 ow;
    ow.x = (unsigned)f2bf(o0) | ((unsigned)f2bf(o1) << 16);
    ow.y = (unsigned)f2bf(o2) | ((unsigned)f2bf(o3) << 16);
    *(uint2*)(actout + (size_t)v*F12 + c0) = ow;
  } else {
    float4 ov = make_float4(o0, o1, o2, o3);
    *(float4*)(fout + (size_t)v*CCH + lane*4) = ov;
  }
}

extern "C" void kernel_launch(void* const* d_in, const int* in_sizes, int n_in,
                              void* d_out, int out_size, void* d_ws, size_t ws_size,
                              hipStream_t stream)
{
  const float* x   = (const float*)d_in[0];
  const int*   ei  = (const int*)d_in[1];
  const float* W1  = (const float*)d_in[2];
  const float* as1 = (const float*)d_in[3];
  const float* ad1 = (const float*)d_in[4];
  const float* b1  = (const float*)d_in[5];
  const float* W2  = (const float*)d_in[6];
  const float* as2 = (const float*)d_in[7];
  const float* ad2 = (const float*)d_in[8];
  const float* b2  = (const float*)d_in[9];
  const float* W3  = (const float*)d_in[10];
  const float* as3 = (const float*)d_in[11];
  const float* ad3 = (const float*)d_in[12];
  const float* b3  = (const float*)d_in[13];
  float* out = (float*)d_out;
  (void)in_sizes; (void)n_in; (void)out_size; (void)ws_size;

  char* p = (char*)d_ws;
  auto carve = [&](size_t bytes)->char* {
    char* r = p; p += (bytes + 255) & ~(size_t)255; return r;
  };
  unsigned short* actA = (unsigned short*)carve((size_t)MPAD*F12*2);
  unsigned short* hbuf = (unsigned short*)carve((size_t)MPAD*F12*2);  // head-major
  unsigned short* Wt1  = (unsigned short*)carve((size_t)F12*DIN*2);
  unsigned short* Wt2  = (unsigned short*)carve((size_t)F12*F12*2);
  unsigned short* Wt3  = (unsigned short*)carve((size_t)CCH*F12*2);
  float* als  = (float*)carve((size_t)NN*NH*4);
  float* ald  = (float*)carve((size_t)NN*NH*4);
  float* Wa1  = (float*)carve((size_t)64*16*4);
  int* deg    = (int*)carve((size_t)NN*4);
  int* cursor = (int*)carve((size_t)NN*4);
  int* off    = (int*)carve((size_t)(NN+1)*4);
  int* csrc   = (int*)carve((size_t)NE*4);
  unsigned short* Xa = hbuf;   // [MPAD][8][64] alias; dead before gemm_l2 writes hbuf

  const int* esrc = ei;
  const int* edst = ei + NE;

  // weight transposes
  transpose_cvt_kernel<<<dim3(DIN/32,  F12/32), 256, 0, stream>>>(W1, Wt1, DIN, F12);
  transpose_cvt_kernel<<<dim3(F12/32,  F12/32), 256, 0, stream>>>(W2, Wt2, F12, F12);
  transpose_cvt_kernel<<<dim3(F12/32,  CCH/32), 256, 0, stream>>>(W3, Wt3, F12, CCH);

  // CSR by dst
  hipMemsetAsync(deg,    0, (size_t)NN*4, stream);
  hipMemsetAsync(cursor, 0, (size_t)NN*4, stream);
  hist_kernel<<<(NE + 255)/256, 256, 0, stream>>>(edst, deg, NE);
  scan_kernel<<<1, 256, 0, stream>>>(deg, off, NN);
  scatter_kernel<<<(NE + 255)/256, 256, 0, stream>>>(esrc, edst, off, cursor, csrc, NE);

  // layer 1 (linearity restructure)
  wa1_kernel<<<4, 256, 0, stream>>>(W1, as1, ad1, Wa1);
  logits1_kernel<<<(NN*16 + 255)/256, 256, 0, stream>>>(x, Wa1, als, ald);
  hipMemsetAsync(Xa + (size_t)NN*512, 0, (size_t)(MPAD-NN)*512*2, stream);
  agg1_kernel<<<(NN + 3)/4, 256, 0, stream>>>(x, off, csrc, als, ald, Xa);
  gemm_l1_kernel<<<dim3(MPAD/128, NH), 256, 0, stream>>>(Xa, Wt1, b1, actA);

  // layer 2 (head-major hbuf; 256 blocks = 32 M x 8 N, XCD owns N col)
  gemm_l2_kernel<<<256, 512, 0, stream>>>(actA, Wt2, hbuf, F12);
  logits_kernel<<<NN*NH/4, 256, 0, stream>>>(hbuf, as2, ad2, als, ald, NH);
  aggw_kernel<8><<<((NN + 3)/4)*8, 256, 0, stream>>>(hbuf, off, csrc, als, ald, b2, actA, nullptr);

  // layer 3 (hbuf row-major [MPAD][256] == head-major with 1 head)
  gemm_bt_kernel<<<dim3(MPAD/128, CCH/128), 256, 0, stream>>>(actA, Wt3, hbuf, F12, CCH);
  logits_kernel<<<NN/4, 256, 0, stream>>>(hbuf, as3, ad3, als, ald, 1);
  aggw_kernel<1><<<(NN + 3)/4, 256, 0, stream>>>(hbuf, off, csrc, als, ald, b3, nullptr, out);
}

// Round 13
// 333.389 us; speedup vs baseline: 1.1154x; 1.1154x over previous
//
#include <hip/hip_runtime.h>

// GAT 3-layer forward, MI355X gfx950.
// R13: gemm_l2 reverted to R11 config (640x128, n-fast XCD chunks -- the
// A-locality-preserving mapping; XCD-owns-column refuted 3x). agg1 rewritten:
// lane=(edge,head) online softmax + LDS alpha staging (64x fewer exp).

typedef __attribute__((ext_vector_type(8))) short bf16x8;
typedef __attribute__((ext_vector_type(4))) float f32x4;

#define DEVINL __device__ __forceinline__

static constexpr int NN   = 10000;
static constexpr int NE   = 160000;
static constexpr int MPAD = 10240;   // 16*640, 80*128
static constexpr int DIN  = 64;
static constexpr int CCH  = 256;
static constexpr int NH   = 8;
static constexpr int F12  = 2048;    // NH * CCH

DEVINL unsigned short f2bf(float x){
  unsigned u = __float_as_uint(x);
  u += 0x7fffu + ((u >> 16) & 1u);           // RNE
  return (unsigned short)(u >> 16);
}
DEVINL float bf2f(unsigned short h){ return __uint_as_float(((unsigned)h) << 16); }

DEVINL void gload_lds16(const unsigned short* g, unsigned short* lds){
  __builtin_amdgcn_global_load_lds(
      (__attribute__((address_space(1))) unsigned int*)(g),
      (__attribute__((address_space(3))) unsigned int*)(lds), 16, 0, 0);
}

// ---- W [K][Nn] f32 -> Wt [Nn][K] bf16
__global__ __launch_bounds__(256) void transpose_cvt_kernel(const float* __restrict__ W,
                                                            unsigned short* __restrict__ Wt,
                                                            int K, int Nn){
  __shared__ float tile[32][33];
  int k0 = blockIdx.x*32, n0 = blockIdx.y*32;
  int tx = threadIdx.x & 31, ty = threadIdx.x >> 5;
  #pragma unroll
  for (int r = ty; r < 32; r += 8) tile[r][tx] = W[(size_t)(k0+r)*Nn + n0 + tx];
  __syncthreads();
  #pragma unroll
  for (int r = ty; r < 32; r += 8) Wt[(size_t)(n0+r)*K + k0 + tx] = f2bf(tile[tx][r]);
}

// ---- CSR build
__global__ __launch_bounds__(256) void hist_kernel(const int* __restrict__ dst,
                                                   int* __restrict__ deg, int E_){
  int i = blockIdx.x*256 + threadIdx.x;
  if (i < E_) atomicAdd(&deg[dst[i]], 1);
}

__global__ __launch_bounds__(256) void scan_kernel(const int* __restrict__ deg,
                                                   int* __restrict__ off, int n){
  const int CH = (n + 255) / 256;
  int t = threadIdx.x;
  int lo = t*CH, hi = min(lo + CH, n);
  int s = 0;
  for (int i = lo; i < hi; i++) s += deg[i];
  __shared__ int ws[256];
  ws[t] = s;
  __syncthreads();
  for (int d = 1; d < 256; d <<= 1){
    int v = (t >= d) ? ws[t-d] : 0;
    __syncthreads();
    ws[t] += v;
    __syncthreads();
  }
  int run = ws[t] - s;
  for (int i = lo; i < hi; i++){ off[i] = run; run += deg[i]; }
  if (t == 255) off[n] = ws[255];
}

__global__ __launch_bounds__(256) void scatter_kernel(const int* __restrict__ src,
                                                      const int* __restrict__ dst,
                                                      const int* __restrict__ off,
                                                      int* __restrict__ cursor,
                                                      int* __restrict__ csrc, int E_){
  int i = blockIdx.x*256 + threadIdx.x;
  if (i >= E_) return;
  int d = dst[i];
  int pI = atomicAdd(&cursor[d], 1);
  csrc[off[d] + pI] = src[i];
}

// ---- Wa1[c][i] = sum_j W1[c][h*256+j] * a1{s,d}[h][j]
__global__ __launch_bounds__(256) void wa1_kernel(const float* __restrict__ W1,
                                                  const float* __restrict__ a1s,
                                                  const float* __restrict__ a1d,
                                                  float* __restrict__ Wa1){
  int t = blockIdx.x*256 + threadIdx.x;
  if (t >= 64*16) return;
  int c = t >> 4, i = t & 15;
  int h = i & 7;
  const float* a = (i < 8) ? a1s : a1d;
  float s = 0.f;
  #pragma unroll 8
  for (int j = 0; j < 256; j++) s = fmaf(W1[(size_t)c*F12 + h*256 + j], a[h*256 + j], s);
  Wa1[c*16 + i] = s;
}

// ---- layer-1 logits straight from x
__global__ __launch_bounds__(256) void logits1_kernel(const float* __restrict__ x,
                                                      const float* __restrict__ Wa1,
                                                      float* __restrict__ als,
                                                      float* __restrict__ ald){
  __shared__ float wa[64*16];
  for (int i = threadIdx.x; i < 64*16; i += 256) wa[i] = Wa1[i];
  __syncthreads();
  int gid = blockIdx.x*256 + threadIdx.x;
  int v = gid >> 4, i = gid & 15;
  if (v >= NN) return;
  float s = 0.f;
  #pragma unroll
  for (int c = 0; c < 64; c++) s = fmaf(x[(size_t)v*64 + c], wa[c*16 + i], s);
  if (i < 8) als[v*8 + i] = s;
  else       ald[v*8 + (i - 8)] = s;
}

// ---- R13 layer-1 aggregation: lane=(edge_slot,head) softmax, LDS alpha stage.
// Per 8-edge chunk: 1 exp per (edge,head) (64 total) instead of 512/edge.
__global__ __launch_bounds__(256) void agg1_kernel(const float* __restrict__ x,
                                                   const int* __restrict__ off,
                                                   const int* __restrict__ csrc,
                                                   const float* __restrict__ als,
                                                   const float* __restrict__ ald,
                                                   unsigned short* __restrict__ Xa){
  const int wv = threadIdx.x >> 6, lane = threadIdx.x & 63;
  const int v = blockIdx.x*4 + wv;
  if (v >= NN) return;
  const int e0 = off[v], deg = off[v+1] - e0;
  const int h  = lane & 7;        // this lane's head (alpha phases)
  const int es = lane >> 3;       // this lane's edge slot 0..7

  __shared__ float al_sh[4][64];  // [wave][es*8+h]
  __shared__ int   u_sh[4][8];

  const float aldv = ald[v*8 + h];

  // pass 1: per-lane online (m,s) over edges es, es+8, ...
  float m = -1e30f, s = 0.f;
  for (int i = es; i < deg; i += 8){
    int u = csrc[e0 + i];
    float xe = als[u*8 + h] + aldv;
    xe = xe > 0.f ? xe : 0.2f*xe;
    float nm = fmaxf(m, xe);
    s = s*__expf(m - nm) + __expf(xe - nm);
    m = nm;
  }
  // merge the 8 edge-slot partials per head (lanes h, h+8, ..., h+56)
  #pragma unroll
  for (int d = 8; d < 64; d <<= 1){
    float mo = __shfl_xor(m, d);
    float so = __shfl_xor(s, d);
    float nm = fmaxf(m, mo);
    s = s*__expf(m - nm) + so*__expf(mo - nm);
    m = nm;
  }
  const float sinv = 1.f / (s + 1e-16f);

  // pass 2: chunks of 8 edges; alpha+u staged in per-wave LDS (wave-sync)
  float acc[8];
  #pragma unroll
  for (int hh = 0; hh < 8; hh++) acc[hh] = 0.f;

  const int nfull = deg & ~7;
  for (int base = 0; base < nfull; base += 8){
    int u = csrc[e0 + base + es];
    if (h == 0) u_sh[wv][es] = u;
    float xe = als[u*8 + h] + aldv;
    xe = xe > 0.f ? xe : 0.2f*xe;
    al_sh[wv][es*8 + h] = __expf(xe - m) * sinv;
    #pragma unroll
    for (int j = 0; j < 8; j++){
      float xv = x[(size_t)u_sh[wv][j]*64 + lane];
      #pragma unroll
      for (int hh = 0; hh < 8; hh++)
        acc[hh] = fmaf(al_sh[wv][j*8 + hh], xv, acc[hh]);
    }
  }
  if (nfull < deg){
    const int nch = deg - nfull;            // 1..7
    if (es < nch){
      int u = csrc[e0 + nfull + es];
      if (h == 0) u_sh[wv][es] = u;
      float xe = als[u*8 + h] + aldv;
      xe = xe > 0.f ? xe : 0.2f*xe;
      al_sh[wv][es*8 + h] = __expf(xe - m) * sinv;
    }
    for (int j = 0; j < nch; j++){
      float xv = x[(size_t)u_sh[wv][j]*64 + lane];
      #pragma unroll
      for (int hh = 0; hh < 8; hh++)
        acc[hh] = fmaf(al_sh[wv][j*8 + hh], xv, acc[hh]);
    }
  }

  #pragma unroll
  for (int hh = 0; hh < 8; hh++)
    Xa[(size_t)v*512 + hh*64 + lane] = f2bf(acc[hh]);
}

// ---- layer-1 GEMM per head with fused bias+ELU
__global__ __launch_bounds__(256) void gemm_l1_kernel(
    const unsigned short* __restrict__ Xa,    // [MPAD][8][64]
    const unsigned short* __restrict__ Wt1,   // [2048][64]
    const float* __restrict__ b1,
    unsigned short* __restrict__ actA)        // [MPAD][2048]
{
  __shared__ __align__(16) unsigned short As[2][128*32];
  __shared__ __align__(16) unsigned short Bs[2][256*32];
  const int wave = threadIdx.x >> 6, lane = threadIdx.x & 63;
  const int wm = wave >> 1, wn = wave & 1;
  const size_t m0 = (size_t)blockIdx.x * 128;
  const int h = blockIdx.y;
  const int lr = lane >> 2, l3 = lane & 3;

  #pragma unroll
  for (int sB = 0; sB < 2; sB++){
    #pragma unroll
    for (int j = 0; j < 2; j++){
      int rb = (wave*2 + j)*16;
      int row = rb + lr;
      int kc = l3 ^ ((row >> 1) & 3);
      gload_lds16(Xa + (m0 + row)*512 + h*64 + sB*32 + kc*8, &As[sB][rb*32]);
    }
    #pragma unroll
    for (int j = 0; j < 4; j++){
      int rb = (wave*4 + j)*16;
      int row = rb + lr;
      int kc = l3 ^ ((row >> 1) & 3);
      gload_lds16(Wt1 + (size_t)(h*256 + row)*64 + sB*32 + kc*8, &Bs[sB][rb*32]);
    }
  }
  asm volatile("s_waitcnt vmcnt(0)" ::: "memory");
  __syncthreads();

  f32x4 acc[4][8];
  #pragma unroll
  for (int i = 0; i < 4; i++)
    #pragma unroll
    for (int j = 0; j < 8; j++) acc[i][j] = (f32x4){0.f,0.f,0.f,0.f};

  const int rl = lane & 15, q = lane >> 4;
  #pragma unroll
  for (int sB = 0; sB < 2; sB++){
    bf16x8 af[4], bfr[8];
    #pragma unroll
    for (int mm = 0; mm < 4; mm++){
      int row = wm*64 + mm*16 + rl;
      int ch = q ^ ((row >> 1) & 3);
      af[mm] = *(const bf16x8*)&As[sB][row*32 + ch*8];
    }
    #pragma unroll
    for (int n = 0; n < 8; n++){
      int row = wn*128 + n*16 + rl;
      int ch = q ^ ((row >> 1) & 3);
      bfr[n] = *(const bf16x8*)&Bs[sB][row*32 + ch*8];
    }
    #pragma unroll
    for (int mm = 0; mm < 4; mm++)
      #pragma unroll
      for (int n = 0; n < 8; n++)
        acc[mm][n] = __builtin_amdgcn_mfma_f32_16x16x32_bf16(af[mm], bfr[n], acc[mm][n], 0, 0, 0);
  }

  #pragma unroll
  for (int mm = 0; mm < 4; mm++)
    #pragma unroll
    for (int n = 0; n < 8; n++)
      #pragma unroll
      for (int r = 0; r < 4; r++){
        size_t row = m0 + wm*64 + mm*16 + q*4 + r;
        int col = wn*128 + n*16 + rl;
        float o = acc[mm][n][r] + b1[h*256 + col];
        o = o > 0.f ? o : (__expf(o) - 1.f);
        actA[row*F12 + h*256 + col] = f2bf(o);
      }
}

// ---- layer-2 GEMM (R11 config): BM=640, BN=128, BK=32 -> grid 256 = 1/CU.
// n-fast XCD chunks (XCD owns 2 M-panels x all 16 N-tiles: A L2-resident).
// Epilogue writes head-major hbuf [8][MPAD][256].
__global__ __launch_bounds__(512, 1) void gemm_l2_kernel(
    const unsigned short* __restrict__ A,
    const unsigned short* __restrict__ Bt,
    unsigned short* __restrict__ Chm,         // [8][MPAD][256]
    int K)
{
  __shared__ __align__(16) unsigned short As[3][640*32];   // 3 x 40KB
  __shared__ __align__(16) unsigned short Bs[3][128*32];   // 3 x 8KB

  const int tid  = threadIdx.x;
  const int wave = tid >> 6, lane = tid & 63;
  const int wm = wave >> 1, wn = wave & 1;          // 4Mx2N, per-wave 160x64

  const int orig = blockIdx.x;
  const int wg   = (orig & 7) * 32 + (orig >> 3);
  const size_t m0 = (size_t)(wg >> 4) * 640;
  const size_t n0 = (size_t)(wg & 15) * 128;

  f32x4 acc[10][4];
  #pragma unroll
  for (int i = 0; i < 10; i++)
    #pragma unroll
    for (int j = 0; j < 4; j++) acc[i][j] = (f32x4){0.f,0.f,0.f,0.f};

  const int lr = lane >> 2;
  const int l3 = lane & 3;

  auto stageA = [&](int slot, int k0, int j){
    const int rb  = (wave*5 + j) * 16;
    const int row = rb + lr;
    const int kc  = l3 ^ ((row >> 1) & 3);
    gload_lds16(A + (m0 + row)*(size_t)K + k0 + kc*8, &As[slot][rb*32]);
  };
  auto stageB = [&](int slot, int k0){
    const int rb  = wave * 16;
    const int row = rb + lr;
    const int kc  = l3 ^ ((row >> 1) & 3);
    gload_lds16(Bt + (n0 + row)*(size_t)K + k0 + kc*8, &Bs[slot][rb*32]);
  };
  auto stageTile = [&](int T){
    const int slot = T % 3, k0 = T << 5;
    #pragma unroll
    for (int j = 0; j < 5; j++) stageA(slot, k0, j);
    stageB(slot, k0);
  };

  const int nt = K >> 5;            // 64
  stageTile(0);
  stageTile(1);

  const int rl = lane & 15;
  const int q  = lane >> 4;

  for (int T = 0; T < nt; ++T){
    if (T + 1 < nt) asm volatile("s_waitcnt vmcnt(6)" ::: "memory");
    else            asm volatile("s_waitcnt vmcnt(0)" ::: "memory");
    __builtin_amdgcn_s_barrier();

    const int slot = T % 3;
    const bool st  = (T + 2 < nt);
    const int s2   = (T + 2) % 3;
    const int k2   = (T + 2) << 5;

    bf16x8 bfr[4], af[5];
    #pragma unroll
    for (int n = 0; n < 4; n++){
      const int row = wn*64 + n*16 + rl;
      const int ch  = q ^ ((row >> 1) & 3);
      bfr[n] = *(const bf16x8*)&Bs[slot][row*32 + ch*8];
    }
    #pragma unroll
    for (int m = 0; m < 5; m++){
      const int row = wm*160 + m*16 + rl;
      const int ch  = q ^ ((row >> 1) & 3);
      af[m] = *(const bf16x8*)&As[slot][row*32 + ch*8];
    }
    if (st){ stageA(s2, k2, 0); stageA(s2, k2, 1); stageA(s2, k2, 2); }
    asm volatile("s_waitcnt lgkmcnt(0)" ::: "memory");
    __builtin_amdgcn_sched_barrier(0);
    __builtin_amdgcn_s_setprio(1);
    #pragma unroll
    for (int m = 0; m < 5; m++)
      #pragma unroll
      for (int n = 0; n < 4; n++)
        acc[m][n] = __builtin_amdgcn_mfma_f32_16x16x32_bf16(af[m], bfr[n], acc[m][n], 0, 0, 0);
    __builtin_amdgcn_s_setprio(0);
    __builtin_amdgcn_sched_barrier(0);
    #pragma unroll
    for (int m = 0; m < 5; m++){
      const int row = wm*160 + (m+5)*16 + rl;
      const int ch  = q ^ ((row >> 1) & 3);
      af[m] = *(const bf16x8*)&As[slot][row*32 + ch*8];
    }
    if (st){ stageA(s2, k2, 3); stageA(s2, k2, 4); stageB(s2, k2); }
    asm volatile("s_waitcnt lgkmcnt(0)" ::: "memory");
    __builtin_amdgcn_sched_barrier(0);
    __builtin_amdgcn_s_setprio(1);
    #pragma unroll
    for (int m = 0; m < 5; m++)
      #pragma unroll
      for (int n = 0; n < 4; n++)
        acc[m+5][n] = __builtin_amdgcn_mfma_f32_16x16x32_bf16(af[m], bfr[n], acc[m+5][n], 0, 0, 0);
    __builtin_amdgcn_s_setprio(0);
  }

  const int head = (int)(n0 >> 8);           // BN=128 within one 256-col head
  #pragma unroll
  for (int m = 0; m < 10; m++)
    #pragma unroll
    for (int n = 0; n < 4; n++)
      #pragma unroll
      for (int r = 0; r < 4; r++){
        size_t row = m0 + wm*160 + m*16 + q*4 + r;
        size_t col = n0 + wn*64  + n*16 + rl;
        int ch = (int)(col & 255);
        Chm[((size_t)head*MPAD + row)*CCH + ch] = f2bf(acc[m][n][r]);
      }
}

// ---- generic 128x128 GEMM (layer 3; row-major C)
__global__ __launch_bounds__(256, 2) void gemm_bt_kernel(
    const unsigned short* __restrict__ A,
    const unsigned short* __restrict__ Bt,
    unsigned short* __restrict__ C,
    int K, int Nn)
{
  __shared__ __align__(16) unsigned short As[2][128*32];
  __shared__ __align__(16) unsigned short Bs[2][128*32];
  const int tid  = threadIdx.x;
  const int wave = tid >> 6, lane = tid & 63;
  const int wr = wave >> 1, wc = wave & 1;
  const size_t m0 = (size_t)blockIdx.x * 128;
  const size_t n0 = (size_t)blockIdx.y * 128;

  const int l4 = lane >> 2;
  const int lc = lane & 3;

  f32x4 acc[4][4];
  #pragma unroll
  for (int i = 0; i < 4; i++)
    #pragma unroll
    for (int j = 0; j < 4; j++) acc[i][j] = (f32x4){0.f,0.f,0.f,0.f};

  auto stage = [&](int buf, int kt){
    const int k0 = kt << 5;
    #pragma unroll
    for (int half = 0; half < 2; ++half){
      const int rb  = (wave + half*4) * 16;
      const int row = rb + l4;
      const int kc  = lc ^ ((row >> 1) & 3);
      gload_lds16(A + ((m0 + row)*(size_t)K + k0 + kc*8), &As[buf][rb*32]);
    }
    #pragma unroll
    for (int half = 0; half < 2; ++half){
      const int rb  = (wave + half*4) * 16;
      const int row = rb + l4;
      const int kc  = lc ^ ((row >> 1) & 3);
      gload_lds16(Bt + ((n0 + row)*(size_t)K + k0 + kc*8), &Bs[buf][rb*32]);
    }
  };

  const int nt = K >> 5;
  stage(0, 0);
  __syncthreads();

  const int rl = lane & 15;
  const int q  = lane >> 4;

  int cur = 0;
  for (int t = 0; t < nt; ++t){
    if (t + 1 < nt) stage(cur ^ 1, t + 1);
    bf16x8 af[4], bfr[4];
    #pragma unroll
    for (int m = 0; m < 4; m++){
      int row = wr*64 + m*16 + rl;
      int ch  = q ^ ((row >> 1) & 3);
      af[m] = *(const bf16x8*)&As[cur][row*32 + ch*8];
    }
    #pragma unroll
    for (int n = 0; n < 4; n++){
      int row = wc*64 + n*16 + rl;
      int ch  = q ^ ((row >> 1) & 3);
      bfr[n] = *(const bf16x8*)&Bs[cur][row*32 + ch*8];
    }
    #pragma unroll
    for (int m = 0; m < 4; m++)
      #pragma unroll
      for (int n = 0; n < 4; n++)
        acc[m][n] = __builtin_amdgcn_mfma_f32_16x16x32_bf16(af[m], bfr[n], acc[m][n], 0, 0, 0);
    __syncthreads();
    cur ^= 1;
  }

  #pragma unroll
  for (int m = 0; m < 4; m++)
    #pragma unroll
    for (int n = 0; n < 4; n++)
      #pragma unroll
      for (int r = 0; r < 4; r++){
        size_t row = m0 + wr*64 + m*16 + q*4 + r;
        size_t col = n0 + wc*64 + n*16 + rl;
        C[row*(size_t)Nn + col] = f2bf(acc[m][n][r]);
      }
}

// ---- attention logits, head-major Hm [heads][MPAD][256]
__global__ __launch_bounds__(256) void logits_kernel(const unsigned short* __restrict__ Hm,
                                                     const float* __restrict__ aws,
                                                     const float* __restrict__ awd,
                                                     float* __restrict__ als,
                                                     float* __restrict__ ald,
                                                     int heads){
  int gw   = (blockIdx.x*256 + threadIdx.x) >> 6;
  int lane = threadIdx.x & 63;
  int node = gw / heads;
  int head = gw - node*heads;
  if (node >= NN) return;
  const unsigned short* hp = Hm + ((size_t)head*MPAD + node)*CCH + lane*4;
  const float* wsp = aws + head*CCH + lane*4;
  const float* wdp = awd + head*CCH + lane*4;
  float s = 0.f, d = 0.f;
  #pragma unroll
  for (int j = 0; j < 4; j++){
    float hv = bf2f(hp[j]);
    s = fmaf(hv, wsp[j], s);
    d = fmaf(hv, wdp[j], d);
  }
  #pragma unroll
  for (int m = 1; m < 64; m <<= 1){ s += __shfl_xor(s, m); d += __shfl_xor(d, m); }
  if (lane == 0){ als[node*heads + head] = s; ald[node*heads + head] = d; }
}

// ---- wave-per-(v,head) segment softmax + aggregation + bias + ELU
template<int NHD>
__global__ __launch_bounds__(256) void aggw_kernel(
    const unsigned short* __restrict__ Hm,
    const int* __restrict__ off, const int* __restrict__ csrc,
    const float* __restrict__ als, const float* __restrict__ ald,
    const float* __restrict__ bias,
    unsigned short* __restrict__ actout,
    float* __restrict__ fout)
{
  const int wv = threadIdx.x >> 6, lane = threadIdx.x & 63;
  int v, h;
  if constexpr (NHD == 8){
    h = blockIdx.x & 7;
    v = (blockIdx.x >> 3) * 4 + wv;
  } else {
    h = 0;
    v = blockIdx.x * 4 + wv;
  }
  if (v >= NN) return;
  const int e0 = off[v], deg = off[v+1] - e0;
  const float aldv = ald[v*NHD + h];

  __shared__ float al_sh[4][64];
  __shared__ int   u_sh[4][64];

  float mloc = -1e30f;
  for (int i = lane; i < deg; i += 64){
    int u = csrc[e0 + i];
    float xe = als[u*NHD + h] + aldv;
    xe = xe > 0.f ? xe : 0.2f*xe;
    mloc = fmaxf(mloc, xe);
  }
  #pragma unroll
  for (int d = 1; d < 64; d <<= 1) mloc = fmaxf(mloc, __shfl_xor(mloc, d));
  float sloc = 0.f;
  for (int i = lane; i < deg; i += 64){
    int u = csrc[e0 + i];
    float xe = als[u*NHD + h] + aldv;
    xe = xe > 0.f ? xe : 0.2f*xe;
    sloc += __expf(xe - mloc);
  }
  #pragma unroll
  for (int d = 1; d < 64; d <<= 1) sloc += __shfl_xor(sloc, d);
  const float sinv = 1.f / (sloc + 1e-16f);

  const unsigned short* hB = Hm + (size_t)h*MPAD*CCH + lane*4;
  float a0c = 0.f, a1c = 0.f, a2c = 0.f, a3c = 0.f;

  for (int base = 0; base < deg; base += 64){
    const int nch = min(deg - base, 64);
    if (lane < nch){
      int u = csrc[e0 + base + lane];
      u_sh[wv][lane] = u;
      float xe = als[u*NHD + h] + aldv;
      xe = xe > 0.f ? xe : 0.2f*xe;
      al_sh[wv][lane] = __expf(xe - mloc) * sinv;
    }
    int j = 0;
    for (; j + 4 <= nch; j += 4){
      const int u0 = u_sh[wv][j],   u1 = u_sh[wv][j+1];
      const int u2 = u_sh[wv][j+2], u3 = u_sh[wv][j+3];
      const float b0 = al_sh[wv][j],   b1v = al_sh[wv][j+1];
      const float b2 = al_sh[wv][j+2], b3v = al_sh[wv][j+3];
      uint2 w0 = *(const uint2*)(hB + (size_t)u0*CCH);
      uint2 w1 = *(const uint2*)(hB + (size_t)u1*CCH);
      uint2 w2 = *(const uint2*)(hB + (size_t)u2*CCH);
      uint2 w3 = *(const uint2*)(hB + (size_t)u3*CCH);
      a0c = fmaf(b0, bf2f((unsigned short)(w0.x & 0xffff)), a0c);
      a1c = fmaf(b0, bf2f((unsigned short)(w0.x >> 16)),    a1c);
      a2c = fmaf(b0, bf2f((unsigned short)(w0.y & 0xffff)), a2c);
      a3c = fmaf(b0, bf2f((unsigned short)(w0.y >> 16)),    a3c);
      a0c = fmaf(b1v, bf2f((unsigned short)(w1.x & 0xffff)), a0c);
      a1c = fmaf(b1v, bf2f((unsigned short)(w1.x >> 16)),    a1c);
      a2c = fmaf(b1v, bf2f((unsigned short)(w1.y & 0xffff)), a2c);
      a3c = fmaf(b1v, bf2f((unsigned short)(w1.y >> 16)),    a3c);
      a0c = fmaf(b2, bf2f((unsigned short)(w2.x & 0xffff)), a0c);
      a1c = fmaf(b2, bf2f((unsigned short)(w2.x >> 16)),    a1c);
      a2c = fmaf(b2, bf2f((unsigned short)(w2.y & 0xffff)), a2c);
      a3c = fmaf(b2, bf2f((unsigned short)(w2.y >> 16)),    a3c);
      a0c = fmaf(b3v, bf2f((unsigned short)(w3.x & 0xffff)), a0c);
      a1c = fmaf(b3v, bf2f((unsigned short)(w3.x >> 16)),    a1c);
      a2c = fmaf(b3v, bf2f((unsigned short)(w3.y & 0xffff)), a2c);
      a3c = fmaf(b3v, bf2f((unsigned short)(w3.y >> 16)),    a3c);
    }
    for (; j < nch; j++){
      const int u = u_sh[wv][j];
      const float a = al_sh[wv][j];
      uint2 w = *(const uint2*)(hB + (size_t)u*CCH);
      a0c = fmaf(a, bf2f((unsigned short)(w.x & 0xffff)), a0c);
      a1c = fmaf(a, bf2f((unsigned short)(w.x >> 16)),    a1c);
      a2c = fmaf(a, bf2f((unsigned short)(w.y & 0xffff)), a2c);
      a3c = fmaf(a, bf2f((unsigned short)(w.y >> 16)),    a3c);
    }
  }

  const int c0 = h*CCH + lane*4;
  float o0 = a0c + bias[c0],     o1 = a1c + bias[c0 + 1];
  float o2 = a2c + bias[c0 + 2], o3 = a3c + bias[c0 + 3];
  o0 = o0 > 0.f ? o0 : (__expf(o0) - 1.f);
  o1 = o1 > 0.f ? o1 : (__expf(o1) - 1.f);
  o2 = o2 > 0.f ? o2 : (__expf(o2) - 1.f);
  o3 = o3 > 0.f ? o3 : (__expf(o3) - 1.f);
  if constexpr (NHD == 8){
    uint2 ow;
    ow.x = (unsigned)f2bf(o0) | ((unsigned)f2bf(o1) << 16);
    ow.y = (unsigned)f2bf(o2) | ((unsigned)f2bf(o3) << 16);
    *(uint2*)(actout + (size_t)v*F12 + c0) = ow;
  } else {
    float4 ov = make_float4(o0, o1, o2, o3);
    *(float4*)(fout + (size_t)v*CCH + lane*4) = ov;
  }
}

extern "C" void kernel_launch(void* const* d_in, const int* in_sizes, int n_in,
                              void* d_out, int out_size, void* d_ws, size_t ws_size,
                              hipStream_t stream)
{
  const float* x   = (const float*)d_in[0];
  const int*   ei  = (const int*)d_in[1];
  const float* W1  = (const float*)d_in[2];
  const float* as1 = (const float*)d_in[3];
  const float* ad1 = (const float*)d_in[4];
  const float* b1  = (const float*)d_in[5];
  const float* W2  = (const float*)d_in[6];
  const float* as2 = (const float*)d_in[7];
  const float* ad2 = (const float*)d_in[8];
  const float* b2  = (const float*)d_in[9];
  const float* W3  = (const float*)d_in[10];
  const float* as3 = (const float*)d_in[11];
  const float* ad3 = (const float*)d_in[12];
  const float* b3  = (const float*)d_in[13];
  float* out = (float*)d_out;
  (void)in_sizes; (void)n_in; (void)out_size; (void)ws_size;

  char* p = (char*)d_ws;
  auto carve = [&](size_t bytes)->char* {
    char* r = p; p += (bytes + 255) & ~(size_t)255; return r;
  };
  unsigned short* actA = (unsigned short*)carve((size_t)MPAD*F12*2);
  unsigned short* hbuf = (unsigned short*)carve((size_t)MPAD*F12*2);  // head-major
  unsigned short* Wt1  = (unsigned short*)carve((size_t)F12*DIN*2);
  unsigned short* Wt2  = (unsigned short*)carve((size_t)F12*F12*2);
  unsigned short* Wt3  = (unsigned short*)carve((size_t)CCH*F12*2);
  float* als  = (float*)carve((size_t)NN*NH*4);
  float* ald  = (float*)carve((size_t)NN*NH*4);
  float* Wa1  = (float*)carve((size_t)64*16*4);
  int* deg    = (int*)carve((size_t)NN*4);
  int* cursor = (int*)carve((size_t)NN*4);
  int* off    = (int*)carve((size_t)(NN+1)*4);
  int* csrc   = (int*)carve((size_t)NE*4);
  unsigned short* Xa = hbuf;   // [MPAD][8][64] alias; dead before gemm_l2 writes hbuf

  const int* esrc = ei;
  const int* edst = ei + NE;

  // weight transposes
  transpose_cvt_kernel<<<dim3(DIN/32,  F12/32), 256, 0, stream>>>(W1, Wt1, DIN, F12);
  transpose_cvt_kernel<<<dim3(F12/32,  F12/32), 256, 0, stream>>>(W2, Wt2, F12, F12);
  transpose_cvt_kernel<<<dim3(F12/32,  CCH/32), 256, 0, stream>>>(W3, Wt3, F12, CCH);

  // CSR by dst
  hipMemsetAsync(deg,    0, (size_t)NN*4, stream);
  hipMemsetAsync(cursor, 0, (size_t)NN*4, stream);
  hist_kernel<<<(NE + 255)/256, 256, 0, stream>>>(edst, deg, NE);
  scan_kernel<<<1, 256, 0, stream>>>(deg, off, NN);
  scatter_kernel<<<(NE + 255)/256, 256, 0, stream>>>(esrc, edst, off, cursor, csrc, NE);

  // layer 1 (linearity restructure)
  wa1_kernel<<<4, 256, 0, stream>>>(W1, as1, ad1, Wa1);
  logits1_kernel<<<(NN*16 + 255)/256, 256, 0, stream>>>(x, Wa1, als, ald);
  hipMemsetAsync(Xa + (size_t)NN*512, 0, (size_t)(MPAD-NN)*512*2, stream);
  agg1_kernel<<<(NN + 3)/4, 256, 0, stream>>>(x, off, csrc, als, ald, Xa);
  gemm_l1_kernel<<<dim3(MPAD/128, NH), 256, 0, stream>>>(Xa, Wt1, b1, actA);

  // layer 2 (head-major hbuf; R11 n-fast XCD-chunk mapping)
  gemm_l2_kernel<<<256, 512, 0, stream>>>(actA, Wt2, hbuf, F12);
  logits_kernel<<<NN*NH/4, 256, 0, stream>>>(hbuf, as2, ad2, als, ald, NH);
  aggw_kernel<8><<<((NN + 3)/4)*8, 256, 0, stream>>>(hbuf, off, csrc, als, ald, b2, actA, nullptr);

  // layer 3 (hbuf row-major [MPAD][256] == head-major with 1 head)
  gemm_bt_kernel<<<dim3(MPAD/128, CCH/128), 256, 0, stream>>>(actA, Wt3, hbuf, F12, CCH);
  logits_kernel<<<NN/4, 256, 0, stream>>>(hbuf, as3, ad3, als, ald, 1);
  aggw_kernel<1><<<(NN + 3)/4, 256, 0, stream>>>(hbuf, off, csrc, als, ald, b3, nullptr, out);
}

// Round 14
// 329.719 us; speedup vs baseline: 1.1278x; 1.0111x over previous
//
#include <hip/hip_runtime.h>

// GAT 3-layer forward, MI355X gfx950.
// R14: aggw rewritten as half-wave edge-pairing: 2 edges/wave-step, 16B
// (uint4) loads per lane (8 ch), x2 unroll, final shfl_xor(32) merge.
// Everything else frozen from R13 (gemm_l2 R11-config, agg1 R13, L1 linearity).

typedef __attribute__((ext_vector_type(8))) short bf16x8;
typedef __attribute__((ext_vector_type(4))) float f32x4;

#define DEVINL __device__ __forceinline__

static constexpr int NN   = 10000;
static constexpr int NE   = 160000;
static constexpr int MPAD = 10240;   // 16*640, 80*128
static constexpr int DIN  = 64;
static constexpr int CCH  = 256;
static constexpr int NH   = 8;
static constexpr int F12  = 2048;    // NH * CCH

DEVINL unsigned short f2bf(float x){
  unsigned u = __float_as_uint(x);
  u += 0x7fffu + ((u >> 16) & 1u);           // RNE
  return (unsigned short)(u >> 16);
}
DEVINL float bf2f(unsigned short h){ return __uint_as_float(((unsigned)h) << 16); }

DEVINL void gload_lds16(const unsigned short* g, unsigned short* lds){
  __builtin_amdgcn_global_load_lds(
      (__attribute__((address_space(1))) unsigned int*)(g),
      (__attribute__((address_space(3))) unsigned int*)(lds), 16, 0, 0);
}

// ---- W [K][Nn] f32 -> Wt [Nn][K] bf16
__global__ __launch_bounds__(256) void transpose_cvt_kernel(const float* __restrict__ W,
                                                            unsigned short* __restrict__ Wt,
                                                            int K, int Nn){
  __shared__ float tile[32][33];
  int k0 = blockIdx.x*32, n0 = blockIdx.y*32;
  int tx = threadIdx.x & 31, ty = threadIdx.x >> 5;
  #pragma unroll
  for (int r = ty; r < 32; r += 8) tile[r][tx] = W[(size_t)(k0+r)*Nn + n0 + tx];
  __syncthreads();
  #pragma unroll
  for (int r = ty; r < 32; r += 8) Wt[(size_t)(n0+r)*K + k0 + tx] = f2bf(tile[tx][r]);
}

// ---- CSR build
__global__ __launch_bounds__(256) void hist_kernel(const int* __restrict__ dst,
                                                   int* __restrict__ deg, int E_){
  int i = blockIdx.x*256 + threadIdx.x;
  if (i < E_) atomicAdd(&deg[dst[i]], 1);
}

__global__ __launch_bounds__(256) void scan_kernel(const int* __restrict__ deg,
                                                   int* __restrict__ off, int n){
  const int CH = (n + 255) / 256;
  int t = threadIdx.x;
  int lo = t*CH, hi = min(lo + CH, n);
  int s = 0;
  for (int i = lo; i < hi; i++) s += deg[i];
  __shared__ int ws[256];
  ws[t] = s;
  __syncthreads();
  for (int d = 1; d < 256; d <<= 1){
    int v = (t >= d) ? ws[t-d] : 0;
    __syncthreads();
    ws[t] += v;
    __syncthreads();
  }
  int run = ws[t] - s;
  for (int i = lo; i < hi; i++){ off[i] = run; run += deg[i]; }
  if (t == 255) off[n] = ws[255];
}

__global__ __launch_bounds__(256) void scatter_kernel(const int* __restrict__ src,
                                                      const int* __restrict__ dst,
                                                      const int* __restrict__ off,
                                                      int* __restrict__ cursor,
                                                      int* __restrict__ csrc, int E_){
  int i = blockIdx.x*256 + threadIdx.x;
  if (i >= E_) return;
  int d = dst[i];
  int pI = atomicAdd(&cursor[d], 1);
  csrc[off[d] + pI] = src[i];
}

// ---- Wa1[c][i] = sum_j W1[c][h*256+j] * a1{s,d}[h][j]
__global__ __launch_bounds__(256) void wa1_kernel(const float* __restrict__ W1,
                                                  const float* __restrict__ a1s,
                                                  const float* __restrict__ a1d,
                                                  float* __restrict__ Wa1){
  int t = blockIdx.x*256 + threadIdx.x;
  if (t >= 64*16) return;
  int c = t >> 4, i = t & 15;
  int h = i & 7;
  const float* a = (i < 8) ? a1s : a1d;
  float s = 0.f;
  #pragma unroll 8
  for (int j = 0; j < 256; j++) s = fmaf(W1[(size_t)c*F12 + h*256 + j], a[h*256 + j], s);
  Wa1[c*16 + i] = s;
}

// ---- layer-1 logits straight from x
__global__ __launch_bounds__(256) void logits1_kernel(const float* __restrict__ x,
                                                      const float* __restrict__ Wa1,
                                                      float* __restrict__ als,
                                                      float* __restrict__ ald){
  __shared__ float wa[64*16];
  for (int i = threadIdx.x; i < 64*16; i += 256) wa[i] = Wa1[i];
  __syncthreads();
  int gid = blockIdx.x*256 + threadIdx.x;
  int v = gid >> 4, i = gid & 15;
  if (v >= NN) return;
  float s = 0.f;
  #pragma unroll
  for (int c = 0; c < 64; c++) s = fmaf(x[(size_t)v*64 + c], wa[c*16 + i], s);
  if (i < 8) als[v*8 + i] = s;
  else       ald[v*8 + (i - 8)] = s;
}

// ---- layer-1 aggregation (R13): lane=(edge_slot,head) softmax, LDS alpha stage
__global__ __launch_bounds__(256) void agg1_kernel(const float* __restrict__ x,
                                                   const int* __restrict__ off,
                                                   const int* __restrict__ csrc,
                                                   const float* __restrict__ als,
                                                   const float* __restrict__ ald,
                                                   unsigned short* __restrict__ Xa){
  const int wv = threadIdx.x >> 6, lane = threadIdx.x & 63;
  const int v = blockIdx.x*4 + wv;
  if (v >= NN) return;
  const int e0 = off[v], deg = off[v+1] - e0;
  const int h  = lane & 7;
  const int es = lane >> 3;

  __shared__ float al_sh[4][64];
  __shared__ int   u_sh[4][8];

  const float aldv = ald[v*8 + h];

  float m = -1e30f, s = 0.f;
  for (int i = es; i < deg; i += 8){
    int u = csrc[e0 + i];
    float xe = als[u*8 + h] + aldv;
    xe = xe > 0.f ? xe : 0.2f*xe;
    float nm = fmaxf(m, xe);
    s = s*__expf(m - nm) + __expf(xe - nm);
    m = nm;
  }
  #pragma unroll
  for (int d = 8; d < 64; d <<= 1){
    float mo = __shfl_xor(m, d);
    float so = __shfl_xor(s, d);
    float nm = fmaxf(m, mo);
    s = s*__expf(m - nm) + so*__expf(mo - nm);
    m = nm;
  }
  const float sinv = 1.f / (s + 1e-16f);

  float acc[8];
  #pragma unroll
  for (int hh = 0; hh < 8; hh++) acc[hh] = 0.f;

  const int nfull = deg & ~7;
  for (int base = 0; base < nfull; base += 8){
    int u = csrc[e0 + base + es];
    if (h == 0) u_sh[wv][es] = u;
    float xe = als[u*8 + h] + aldv;
    xe = xe > 0.f ? xe : 0.2f*xe;
    al_sh[wv][es*8 + h] = __expf(xe - m) * sinv;
    #pragma unroll
    for (int j = 0; j < 8; j++){
      float xv = x[(size_t)u_sh[wv][j]*64 + lane];
      #pragma unroll
      for (int hh = 0; hh < 8; hh++)
        acc[hh] = fmaf(al_sh[wv][j*8 + hh], xv, acc[hh]);
    }
  }
  if (nfull < deg){
    const int nch = deg - nfull;
    if (es < nch){
      int u = csrc[e0 + nfull + es];
      if (h == 0) u_sh[wv][es] = u;
      float xe = als[u*8 + h] + aldv;
      xe = xe > 0.f ? xe : 0.2f*xe;
      al_sh[wv][es*8 + h] = __expf(xe - m) * sinv;
    }
    for (int j = 0; j < nch; j++){
      float xv = x[(size_t)u_sh[wv][j]*64 + lane];
      #pragma unroll
      for (int hh = 0; hh < 8; hh++)
        acc[hh] = fmaf(al_sh[wv][j*8 + hh], xv, acc[hh]);
    }
  }

  #pragma unroll
  for (int hh = 0; hh < 8; hh++)
    Xa[(size_t)v*512 + hh*64 + lane] = f2bf(acc[hh]);
}

// ---- layer-1 GEMM per head with fused bias+ELU
__global__ __launch_bounds__(256) void gemm_l1_kernel(
    const unsigned short* __restrict__ Xa,    // [MPAD][8][64]
    const unsigned short* __restrict__ Wt1,   // [2048][64]
    const float* __restrict__ b1,
    unsigned short* __restrict__ actA)        // [MPAD][2048]
{
  __shared__ __align__(16) unsigned short As[2][128*32];
  __shared__ __align__(16) unsigned short Bs[2][256*32];
  const int wave = threadIdx.x >> 6, lane = threadIdx.x & 63;
  const int wm = wave >> 1, wn = wave & 1;
  const size_t m0 = (size_t)blockIdx.x * 128;
  const int h = blockIdx.y;
  const int lr = lane >> 2, l3 = lane & 3;

  #pragma unroll
  for (int sB = 0; sB < 2; sB++){
    #pragma unroll
    for (int j = 0; j < 2; j++){
      int rb = (wave*2 + j)*16;
      int row = rb + lr;
      int kc = l3 ^ ((row >> 1) & 3);
      gload_lds16(Xa + (m0 + row)*512 + h*64 + sB*32 + kc*8, &As[sB][rb*32]);
    }
    #pragma unroll
    for (int j = 0; j < 4; j++){
      int rb = (wave*4 + j)*16;
      int row = rb + lr;
      int kc = l3 ^ ((row >> 1) & 3);
      gload_lds16(Wt1 + (size_t)(h*256 + row)*64 + sB*32 + kc*8, &Bs[sB][rb*32]);
    }
  }
  asm volatile("s_waitcnt vmcnt(0)" ::: "memory");
  __syncthreads();

  f32x4 acc[4][8];
  #pragma unroll
  for (int i = 0; i < 4; i++)
    #pragma unroll
    for (int j = 0; j < 8; j++) acc[i][j] = (f32x4){0.f,0.f,0.f,0.f};

  const int rl = lane & 15, q = lane >> 4;
  #pragma unroll
  for (int sB = 0; sB < 2; sB++){
    bf16x8 af[4], bfr[8];
    #pragma unroll
    for (int mm = 0; mm < 4; mm++){
      int row = wm*64 + mm*16 + rl;
      int ch = q ^ ((row >> 1) & 3);
      af[mm] = *(const bf16x8*)&As[sB][row*32 + ch*8];
    }
    #pragma unroll
    for (int n = 0; n < 8; n++){
      int row = wn*128 + n*16 + rl;
      int ch = q ^ ((row >> 1) & 3);
      bfr[n] = *(const bf16x8*)&Bs[sB][row*32 + ch*8];
    }
    #pragma unroll
    for (int mm = 0; mm < 4; mm++)
      #pragma unroll
      for (int n = 0; n < 8; n++)
        acc[mm][n] = __builtin_amdgcn_mfma_f32_16x16x32_bf16(af[mm], bfr[n], acc[mm][n], 0, 0, 0);
  }

  #pragma unroll
  for (int mm = 0; mm < 4; mm++)
    #pragma unroll
    for (int n = 0; n < 8; n++)
      #pragma unroll
      for (int r = 0; r < 4; r++){
        size_t row = m0 + wm*64 + mm*16 + q*4 + r;
        int col = wn*128 + n*16 + rl;
        float o = acc[mm][n][r] + b1[h*256 + col];
        o = o > 0.f ? o : (__expf(o) - 1.f);
        actA[row*F12 + h*256 + col] = f2bf(o);
      }
}

// ---- layer-2 GEMM (R11 config): BM=640, BN=128, BK=32 -> grid 256 = 1/CU.
__global__ __launch_bounds__(512, 1) void gemm_l2_kernel(
    const unsigned short* __restrict__ A,
    const unsigned short* __restrict__ Bt,
    unsigned short* __restrict__ Chm,         // [8][MPAD][256]
    int K)
{
  __shared__ __align__(16) unsigned short As[3][640*32];   // 3 x 40KB
  __shared__ __align__(16) unsigned short Bs[3][128*32];   // 3 x 8KB

  const int tid  = threadIdx.x;
  const int wave = tid >> 6, lane = tid & 63;
  const int wm = wave >> 1, wn = wave & 1;          // 4Mx2N, per-wave 160x64

  const int orig = blockIdx.x;
  const int wg   = (orig & 7) * 32 + (orig >> 3);
  const size_t m0 = (size_t)(wg >> 4) * 640;
  const size_t n0 = (size_t)(wg & 15) * 128;

  f32x4 acc[10][4];
  #pragma unroll
  for (int i = 0; i < 10; i++)
    #pragma unroll
    for (int j = 0; j < 4; j++) acc[i][j] = (f32x4){0.f,0.f,0.f,0.f};

  const int lr = lane >> 2;
  const int l3 = lane & 3;

  auto stageA = [&](int slot, int k0, int j){
    const int rb  = (wave*5 + j) * 16;
    const int row = rb + lr;
    const int kc  = l3 ^ ((row >> 1) & 3);
    gload_lds16(A + (m0 + row)*(size_t)K + k0 + kc*8, &As[slot][rb*32]);
  };
  auto stageB = [&](int slot, int k0){
    const int rb  = wave * 16;
    const int row = rb + lr;
    const int kc  = l3 ^ ((row >> 1) & 3);
    gload_lds16(Bt + (n0 + row)*(size_t)K + k0 + kc*8, &Bs[slot][rb*32]);
  };
  auto stageTile = [&](int T){
    const int slot = T % 3, k0 = T << 5;
    #pragma unroll
    for (int j = 0; j < 5; j++) stageA(slot, k0, j);
    stageB(slot, k0);
  };

  const int nt = K >> 5;            // 64
  stageTile(0);
  stageTile(1);

  const int rl = lane & 15;
  const int q  = lane >> 4;

  for (int T = 0; T < nt; ++T){
    if (T + 1 < nt) asm volatile("s_waitcnt vmcnt(6)" ::: "memory");
    else            asm volatile("s_waitcnt vmcnt(0)" ::: "memory");
    __builtin_amdgcn_s_barrier();

    const int slot = T % 3;
    const bool st  = (T + 2 < nt);
    const int s2   = (T + 2) % 3;
    const int k2   = (T + 2) << 5;

    bf16x8 bfr[4], af[5];
    #pragma unroll
    for (int n = 0; n < 4; n++){
      const int row = wn*64 + n*16 + rl;
      const int ch  = q ^ ((row >> 1) & 3);
      bfr[n] = *(const bf16x8*)&Bs[slot][row*32 + ch*8];
    }
    #pragma unroll
    for (int m = 0; m < 5; m++){
      const int row = wm*160 + m*16 + rl;
      const int ch  = q ^ ((row >> 1) & 3);
      af[m] = *(const bf16x8*)&As[slot][row*32 + ch*8];
    }
    if (st){ stageA(s2, k2, 0); stageA(s2, k2, 1); stageA(s2, k2, 2); }
    asm volatile("s_waitcnt lgkmcnt(0)" ::: "memory");
    __builtin_amdgcn_sched_barrier(0);
    __builtin_amdgcn_s_setprio(1);
    #pragma unroll
    for (int m = 0; m < 5; m++)
      #pragma unroll
      for (int n = 0; n < 4; n++)
        acc[m][n] = __builtin_amdgcn_mfma_f32_16x16x32_bf16(af[m], bfr[n], acc[m][n], 0, 0, 0);
    __builtin_amdgcn_s_setprio(0);
    __builtin_amdgcn_sched_barrier(0);
    #pragma unroll
    for (int m = 0; m < 5; m++){
      const int row = wm*160 + (m+5)*16 + rl;
      const int ch  = q ^ ((row >> 1) & 3);
      af[m] = *(const bf16x8*)&As[slot][row*32 + ch*8];
    }
    if (st){ stageA(s2, k2, 3); stageA(s2, k2, 4); stageB(s2, k2); }
    asm volatile("s_waitcnt lgkmcnt(0)" ::: "memory");
    __builtin_amdgcn_sched_barrier(0);
    __builtin_amdgcn_s_setprio(1);
    #pragma unroll
    for (int m = 0; m < 5; m++)
      #pragma unroll
      for (int n = 0; n < 4; n++)
        acc[m+5][n] = __builtin_amdgcn_mfma_f32_16x16x32_bf16(af[m], bfr[n], acc[m+5][n], 0, 0, 0);
    __builtin_amdgcn_s_setprio(0);
  }

  const int head = (int)(n0 >> 8);
  #pragma unroll
  for (int m = 0; m < 10; m++)
    #pragma unroll
    for (int n = 0; n < 4; n++)
      #pragma unroll
      for (int r = 0; r < 4; r++){
        size_t row = m0 + wm*160 + m*16 + q*4 + r;
        size_t col = n0 + wn*64  + n*16 + rl;
        int ch = (int)(col & 255);
        Chm[((size_t)head*MPAD + row)*CCH + ch] = f2bf(acc[m][n][r]);
      }
}

// ---- generic 128x128 GEMM (layer 3; row-major C)
__global__ __launch_bounds__(256, 2) void gemm_bt_kernel(
    const unsigned short* __restrict__ A,
    const unsigned short* __restrict__ Bt,
    unsigned short* __restrict__ C,
    int K, int Nn)
{
  __shared__ __align__(16) unsigned short As[2][128*32];
  __shared__ __align__(16) unsigned short Bs[2][128*32];
  const int tid  = threadIdx.x;
  const int wave = tid >> 6, lane = tid & 63;
  const int wr = wave >> 1, wc = wave & 1;
  const size_t m0 = (size_t)blockIdx.x * 128;
  const size_t n0 = (size_t)blockIdx.y * 128;

  const int l4 = lane >> 2;
  const int lc = lane & 3;

  f32x4 acc[4][4];
  #pragma unroll
  for (int i = 0; i < 4; i++)
    #pragma unroll
    for (int j = 0; j < 4; j++) acc[i][j] = (f32x4){0.f,0.f,0.f,0.f};

  auto stage = [&](int buf, int kt){
    const int k0 = kt << 5;
    #pragma unroll
    for (int half = 0; half < 2; ++half){
      const int rb  = (wave + half*4) * 16;
      const int row = rb + l4;
      const int kc  = lc ^ ((row >> 1) & 3);
      gload_lds16(A + ((m0 + row)*(size_t)K + k0 + kc*8), &As[buf][rb*32]);
    }
    #pragma unroll
    for (int half = 0; half < 2; ++half){
      const int rb  = (wave + half*4) * 16;
      const int row = rb + l4;
      const int kc  = lc ^ ((row >> 1) & 3);
      gload_lds16(Bt + ((n0 + row)*(size_t)K + k0 + kc*8), &Bs[buf][rb*32]);
    }
  };

  const int nt = K >> 5;
  stage(0, 0);
  __syncthreads();

  const int rl = lane & 15;
  const int q  = lane >> 4;

  int cur = 0;
  for (int t = 0; t < nt; ++t){
    if (t + 1 < nt) stage(cur ^ 1, t + 1);
    bf16x8 af[4], bfr[4];
    #pragma unroll
    for (int m = 0; m < 4; m++){
      int row = wr*64 + m*16 + rl;
      int ch  = q ^ ((row >> 1) & 3);
      af[m] = *(const bf16x8*)&As[cur][row*32 + ch*8];
    }
    #pragma unroll
    for (int n = 0; n < 4; n++){
      int row = wc*64 + n*16 + rl;
      int ch  = q ^ ((row >> 1) & 3);
      bfr[n] = *(const bf16x8*)&Bs[cur][row*32 + ch*8];
    }
    #pragma unroll
    for (int m = 0; m < 4; m++)
      #pragma unroll
      for (int n = 0; n < 4; n++)
        acc[m][n] = __builtin_amdgcn_mfma_f32_16x16x32_bf16(af[m], bfr[n], acc[m][n], 0, 0, 0);
    __syncthreads();
    cur ^= 1;
  }

  #pragma unroll
  for (int m = 0; m < 4; m++)
    #pragma unroll
    for (int n = 0; n < 4; n++)
      #pragma unroll
      for (int r = 0; r < 4; r++){
        size_t row = m0 + wr*64 + m*16 + q*4 + r;
        size_t col = n0 + wc*64 + n*16 + rl;
        C[row*(size_t)Nn + col] = f2bf(acc[m][n][r]);
      }
}

// ---- attention logits, head-major Hm [heads][MPAD][256]
__global__ __launch_bounds__(256) void logits_kernel(const unsigned short* __restrict__ Hm,
                                                     const float* __restrict__ aws,
                                                     const float* __restrict__ awd,
                                                     float* __restrict__ als,
                                                     float* __restrict__ ald,
                                                     int heads){
  int gw   = (blockIdx.x*256 + threadIdx.x) >> 6;
  int lane = threadIdx.x & 63;
  int node = gw / heads;
  int head = gw - node*heads;
  if (node >= NN) return;
  const unsigned short* hp = Hm + ((size_t)head*MPAD + node)*CCH + lane*4;
  const float* wsp = aws + head*CCH + lane*4;
  const float* wdp = awd + head*CCH + lane*4;
  float s = 0.f, d = 0.f;
  #pragma unroll
  for (int j = 0; j < 4; j++){
    float hv = bf2f(hp[j]);
    s = fmaf(hv, wsp[j], s);
    d = fmaf(hv, wdp[j], d);
  }
  #pragma unroll
  for (int m = 1; m < 64; m <<= 1){ s += __shfl_xor(s, m); d += __shfl_xor(d, m); }
  if (lane == 0){ als[node*heads + head] = s; ald[node*heads + head] = d; }
}

// ---- R14: half-wave edge-paired segment softmax + aggregation.
// Wave = (v,h). Lanes: hl=lane>>5 picks edge parity, li=lane&31 covers
// channels li*8..li*8+7 via one uint4 (16B) load. x2 unroll = 4 edges in
// flight / 2 loads per lane. Final shfl_xor(32) merges even/odd partials.
template<int NHD>
__global__ __launch_bounds__(256) void aggw_kernel(
    const unsigned short* __restrict__ Hm,
    const int* __restrict__ off, const int* __restrict__ csrc,
    const float* __restrict__ als, const float* __restrict__ ald,
    const float* __restrict__ bias,
    unsigned short* __restrict__ actout,
    float* __restrict__ fout)
{
  const int wv = threadIdx.x >> 6, lane = threadIdx.x & 63;
  const int hl = lane >> 5;        // edge parity slot (0/1)
  const int li = lane & 31;        // channel group: ch li*8 .. li*8+7
  int v, h;
  if constexpr (NHD == 8){
    h = blockIdx.x & 7;
    v = (blockIdx.x >> 3) * 4 + wv;
  } else {
    h = 0;
    v = blockIdx.x * 4 + wv;
  }
  if (v >= NN) return;
  const int e0 = off[v], deg = off[v+1] - e0;
  const float aldv = ald[v*NHD + h];

  __shared__ float al_sh[4][64];
  __shared__ int   u_sh[4][64];

  // pass 1: softmax stats (all 64 lanes, shfl reduce)
  float mloc = -1e30f;
  for (int i = lane; i < deg; i += 64){
    int u = csrc[e0 + i];
    float xe = als[u*NHD + h] + aldv;
    xe = xe > 0.f ? xe : 0.2f*xe;
    mloc = fmaxf(mloc, xe);
  }
  #pragma unroll
  for (int d = 1; d < 64; d <<= 1) mloc = fmaxf(mloc, __shfl_xor(mloc, d));
  float sloc = 0.f;
  for (int i = lane; i < deg; i += 64){
    int u = csrc[e0 + i];
    float xe = als[u*NHD + h] + aldv;
    xe = xe > 0.f ? xe : 0.2f*xe;
    sloc += __expf(xe - mloc);
  }
  #pragma unroll
  for (int d = 1; d < 64; d <<= 1) sloc += __shfl_xor(sloc, d);
  const float sinv = 1.f / (sloc + 1e-16f);

  // pass 2: half-wave edge-paired gather
  const unsigned short* hB = Hm + (size_t)h*MPAD*CCH + li*8;
  float acc[8];
  #pragma unroll
  for (int k = 0; k < 8; k++) acc[k] = 0.f;

  auto edge_fma = [&](const uint4& w, float a){
    acc[0] = fmaf(a, bf2f((unsigned short)(w.x & 0xffff)), acc[0]);
    acc[1] = fmaf(a, bf2f((unsigned short)(w.x >> 16)),    acc[1]);
    acc[2] = fmaf(a, bf2f((unsigned short)(w.y & 0xffff)), acc[2]);
    acc[3] = fmaf(a, bf2f((unsigned short)(w.y >> 16)),    acc[3]);
    acc[4] = fmaf(a, bf2f((unsigned short)(w.z & 0xffff)), acc[4]);
    acc[5] = fmaf(a, bf2f((unsigned short)(w.z >> 16)),    acc[5]);
    acc[6] = fmaf(a, bf2f((unsigned short)(w.w & 0xffff)), acc[6]);
    acc[7] = fmaf(a, bf2f((unsigned short)(w.w >> 16)),    acc[7]);
  };

  for (int base = 0; base < deg; base += 64){
    const int nch = min(deg - base, 64);
    if (lane < nch){
      int u = csrc[e0 + base + lane];
      u_sh[wv][lane] = u;
      float xe = als[u*NHD + h] + aldv;
      xe = xe > 0.f ? xe : 0.2f*xe;
      al_sh[wv][lane] = __expf(xe - mloc) * sinv;
    }
    int j = 0;
    for (; j + 4 <= nch; j += 4){
      const int   ua = u_sh[wv][j + hl],     ub = u_sh[wv][j + 2 + hl];
      const float aa = al_sh[wv][j + hl],    ab = al_sh[wv][j + 2 + hl];
      uint4 wA = *(const uint4*)(hB + (size_t)ua*CCH);
      uint4 wB = *(const uint4*)(hB + (size_t)ub*CCH);
      edge_fma(wA, aa);
      edge_fma(wB, ab);
    }
    for (; j + 2 <= nch; j += 2){
      const int   ua = u_sh[wv][j + hl];
      const float aa = al_sh[wv][j + hl];
      uint4 wA = *(const uint4*)(hB + (size_t)ua*CCH);
      edge_fma(wA, aa);
    }
    if (j < nch && hl == 0){      // single leftover edge: half-wave only
      const int   ua = u_sh[wv][j];
      const float aa = al_sh[wv][j];
      uint4 wA = *(const uint4*)(hB + (size_t)ua*CCH);
      edge_fma(wA, aa);
    }
  }

  // merge even/odd-edge partials across the half-wave boundary
  #pragma unroll
  for (int k = 0; k < 8; k++) acc[k] += __shfl_xor(acc[k], 32);

  if (hl == 0){
    const int c0 = h*CCH + li*8;
    float o[8];
    #pragma unroll
    for (int k = 0; k < 8; k++){
      o[k] = acc[k] + bias[c0 + k];
      o[k] = o[k] > 0.f ? o[k] : (__expf(o[k]) - 1.f);
    }
    if constexpr (NHD == 8){
      bf16x8 ov;
      #pragma unroll
      for (int k = 0; k < 8; k++) ov[k] = (short)f2bf(o[k]);
      *(bf16x8*)&actout[(size_t)v*F12 + c0] = ov;
    } else {
      float4 o0 = make_float4(o[0], o[1], o[2], o[3]);
      float4 o1 = make_float4(o[4], o[5], o[6], o[7]);
      *(float4*)(fout + (size_t)v*CCH + li*8)     = o0;
      *(float4*)(fout + (size_t)v*CCH + li*8 + 4) = o1;
    }
  }
}

extern "C" void kernel_launch(void* const* d_in, const int* in_sizes, int n_in,
                              void* d_out, int out_size, void* d_ws, size_t ws_size,
                              hipStream_t stream)
{
  const float* x   = (const float*)d_in[0];
  const int*   ei  = (const int*)d_in[1];
  const float* W1  = (const float*)d_in[2];
  const float* as1 = (const float*)d_in[3];
  const float* ad1 = (const float*)d_in[4];
  const float* b1  = (const float*)d_in[5];
  const float* W2  = (const float*)d_in[6];
  const float* as2 = (const float*)d_in[7];
  const float* ad2 = (const float*)d_in[8];
  const float* b2  = (const float*)d_in[9];
  const float* W3  = (const float*)d_in[10];
  const float* as3 = (const float*)d_in[11];
  const float* ad3 = (const float*)d_in[12];
  const float* b3  = (const float*)d_in[13];
  float* out = (float*)d_out;
  (void)in_sizes; (void)n_in; (void)out_size; (void)ws_size;

  char* p = (char*)d_ws;
  auto carve = [&](size_t bytes)->char* {
    char* r = p; p += (bytes + 255) & ~(size_t)255; return r;
  };
  unsigned short* actA = (unsigned short*)carve((size_t)MPAD*F12*2);
  unsigned short* hbuf = (unsigned short*)carve((size_t)MPAD*F12*2);  // head-major
  unsigned short* Wt1  = (unsigned short*)carve((size_t)F12*DIN*2);
  unsigned short* Wt2  = (unsigned short*)carve((size_t)F12*F12*2);
  unsigned short* Wt3  = (unsigned short*)carve((size_t)CCH*F12*2);
  float* als  = (float*)carve((size_t)NN*NH*4);
  float* ald  = (float*)carve((size_t)NN*NH*4);
  float* Wa1  = (float*)carve((size_t)64*16*4);
  int* deg    = (int*)carve((size_t)NN*4);
  int* cursor = (int*)carve((size_t)NN*4);
  int* off    = (int*)carve((size_t)(NN+1)*4);
  int* csrc   = (int*)carve((size_t)NE*4);
  unsigned short* Xa = hbuf;   // [MPAD][8][64] alias; dead before gemm_l2 writes hbuf

  const int* esrc = ei;
  const int* edst = ei + NE;

  // weight transposes
  transpose_cvt_kernel<<<dim3(DIN/32,  F12/32), 256, 0, stream>>>(W1, Wt1, DIN, F12);
  transpose_cvt_kernel<<<dim3(F12/32,  F12/32), 256, 0, stream>>>(W2, Wt2, F12, F12);
  transpose_cvt_kernel<<<dim3(F12/32,  CCH/32), 256, 0, stream>>>(W3, Wt3, F12, CCH);

  // CSR by dst
  hipMemsetAsync(deg,    0, (size_t)NN*4, stream);
  hipMemsetAsync(cursor, 0, (size_t)NN*4, stream);
  hist_kernel<<<(NE + 255)/256, 256, 0, stream>>>(edst, deg, NE);
  scan_kernel<<<1, 256, 0, stream>>>(deg, off, NN);
  scatter_kernel<<<(NE + 255)/256, 256, 0, stream>>>(esrc, edst, off, cursor, csrc, NE);

  // layer 1 (linearity restructure)
  wa1_kernel<<<4, 256, 0, stream>>>(W1, as1, ad1, Wa1);
  logits1_kernel<<<(NN*16 + 255)/256, 256, 0, stream>>>(x, Wa1, als, ald);
  hipMemsetAsync(Xa + (size_t)NN*512, 0, (size_t)(MPAD-NN)*512*2, stream);
  agg1_kernel<<<(NN + 3)/4, 256, 0, stream>>>(x, off, csrc, als, ald, Xa);
  gemm_l1_kernel<<<dim3(MPAD/128, NH), 256, 0, stream>>>(Xa, Wt1, b1, actA);

  // layer 2 (head-major hbuf; n-fast XCD-chunk mapping)
  gemm_l2_kernel<<<256, 512, 0, stream>>>(actA, Wt2, hbuf, F12);
  logits_kernel<<<NN*NH/4, 256, 0, stream>>>(hbuf, as2, ad2, als, ald, NH);
  aggw_kernel<8><<<((NN + 3)/4)*8, 256, 0, stream>>>(hbuf, off, csrc, als, ald, b2, actA, nullptr);

  // layer 3 (hbuf row-major [MPAD][256] == head-major with 1 head)
  gemm_bt_kernel<<<dim3(MPAD/128, CCH/128), 256, 0, stream>>>(actA, Wt3, hbuf, F12, CCH);
  logits_kernel<<<NN/4, 256, 0, stream>>>(hbuf, as3, ad3, als, ald, 1);
  aggw_kernel<1><<<(NN + 3)/4, 256, 0, stream>>>(hbuf, off, csrc, als, ald, b3, nullptr, out);
}